// Round 1
// baseline (433.924 us; speedup 1.0000x reference)
//
#include <hip/hip_runtime.h>

// AutoEncoderLoss: two-level segment-mean MSE over seg = b*128 + c.
// Per-half-wave-replicated LDS histogram of PACKED u64 accumulators:
//   enc = (1 << 44) | round(d^2 * 2^20)   (count high bits, fixed-point sum low)
// -> ONE native ds_add_u64 per element. batch_index sorted -> per-block chunk
// is single-batch except ~31/2048 boundary blocks.
// Finalize fused via last-block-done pattern (threadfence + atomic counter;
// gseg read back with atomicAdd(p,0) so reads hit the coherent point - safe
// across non-coherent per-XCD L2s).

#define BATCHES 32
#define CLUSTERS 128
#define NSEG (BATCHES * CLUSTERS)
#define BLOCK 256
#define EPB 4096                     // elements per block = 256 thr x 4 iter x 4
#define REPL 8                       // 4 waves x 2 half-waves
#define RSTRIDE (2 * CLUSTERS + 4)   // 260 u64 = 520 dwords = 8 mod 32 banks:
                                     // pad shifts each replica's bank phase
#define SHIFT 44
#define SCALE 1048576.0f             // 2^20
#define INV_SCALE (1.0f / 1048576.0f)
#define SUM_MASK ((1ULL << SHIFT) - 1)

typedef unsigned long long u64;

__device__ __forceinline__ u64 enc_elem(float d) {
    return (1ULL << SHIFT) + (u64)__float2uint_rn(d * d * SCALE);
}

__global__ __launch_bounds__(BLOCK) void seg_loss_kernel(
    const float* __restrict__ reco,
    const float* __restrict__ target,
    const int* __restrict__ clabel,
    const int* __restrict__ batch_index,
    u64* __restrict__ gseg,
    unsigned* __restrict__ done_ctr,
    float* __restrict__ out,
    int n)
{
    __shared__ u64 hist[REPL * RSTRIDE];
    __shared__ float bl[BATCHES];
    __shared__ float bp[BATCHES];
    __shared__ int is_last;

    const int tid = threadIdx.x;

    for (int s = tid; s < REPL * RSTRIDE; s += BLOCK)
        hist[s] = 0ULL;
    __syncthreads();

    // grid is exactly ceil(n/EPB): every block has base < n
    const long long base = (long long)blockIdx.x * EPB;
    const long long lim = (base + EPB <= (long long)n) ? base + EPB : (long long)n;

    const int b0 = batch_index[base];
    const int bL = batch_index[lim - 1];
    u64* h = &hist[(tid >> 5) * RSTRIDE];   // replica id 0..7 = wave*2 + half

    if (b0 == bL && base + EPB <= (long long)n) {
        // single-batch full chunk: no per-element batch load
        #pragma unroll
        for (int k = 0; k < EPB / (BLOCK * 4); ++k) {
            const long long idx = base + (long long)(k * BLOCK + tid) * 4;
            const float4 r = *(const float4*)(reco + idx);
            const float4 t = *(const float4*)(target + idx);
            const int4   c = *(const int4*)(clabel + idx);
            atomicAdd(&h[c.x], enc_elem(r.x - t.x));
            atomicAdd(&h[c.y], enc_elem(r.y - t.y));
            atomicAdd(&h[c.z], enc_elem(r.z - t.z));
            atomicAdd(&h[c.w], enc_elem(r.w - t.w));
        }
    } else {
        // boundary / tail path (rare): per-element batch
        for (long long idx = base + tid; idx < lim; idx += BLOCK) {
            const float d = reco[idx] - target[idx];
            const int b = batch_index[idx];
            const int c = clabel[idx];
            const u64 enc = enc_elem(d);
            const int rel = b - b0;
            if (rel < 2) atomicAdd(&h[rel * CLUSTERS + c], enc);
            else         atomicAdd(&gseg[(long long)b * CLUSTERS + c], enc); // ~never
        }
    }
    __syncthreads();

    // combine replicas, sparse flush (zero entries skipped -> no OOB for the
    // unused upper half when b0 is the last batch)
    for (int s = tid; s < 2 * CLUSTERS; s += BLOCK) {
        u64 v = 0ULL;
        #pragma unroll
        for (int r = 0; r < REPL; ++r) v += hist[r * RSTRIDE + s];
        if (v) atomicAdd(&gseg[(long long)b0 * CLUSTERS + s], v);
    }
    __threadfence();          // make this block's gseg atomics globally visible
    __syncthreads();

    if (tid == 0) {
        const unsigned old = atomicAdd(done_ctr, 1u);
        is_last = (old == gridDim.x - 1) ? 1 : 0;
    }
    __syncthreads();
    if (!is_last) return;
    __threadfence();

    // ---- finalize: only the last-finishing block runs this ----
    const int b    = tid >> 3;   // 32 batches x 8 threads
    const int part = tid & 7;

    float sm = 0.0f, np = 0.0f;
    #pragma unroll
    for (int j = 0; j < 16; ++j) {
        // atomic read -> coherent across XCDs
        const u64 v = atomicAdd(&gseg[b * CLUSTERS + part * 16 + j], 0ULL);
        if (v) {  // nonzero iff count > 0
            const float cnt = (float)(unsigned)(v >> SHIFT);
            const float sum = (float)(v & SUM_MASK) * INV_SCALE;
            sm += sum / cnt;
            np += 1.0f;
        }
    }
    #pragma unroll
    for (int off = 4; off; off >>= 1) {
        sm += __shfl_down(sm, off, 8);
        np += __shfl_down(np, off, 8);
    }
    if (part == 0) {
        bl[b] = (np > 0.0f) ? (sm / np) : 0.0f;
        bp[b] = (np > 0.0f) ? 1.0f : 0.0f;
    }
    __syncthreads();

    if (tid == 0) {
        float s = 0.0f, nb = 0.0f;
        #pragma unroll
        for (int i = 0; i < BATCHES; ++i) { s += bl[i]; nb += bp[i]; }
        out[0] = (nb > 0.0f) ? (s / nb) : 0.0f;
    }
}

extern "C" void kernel_launch(void* const* d_in, const int* in_sizes, int n_in,
                              void* d_out, int out_size, void* d_ws, size_t ws_size,
                              hipStream_t stream) {
    const float* reco        = (const float*)d_in[0];
    const float* target      = (const float*)d_in[1];
    const int*   clabel      = (const int*)d_in[2];
    const int*   batch_index = (const int*)d_in[3];
    const int n = in_sizes[0];

    u64* gseg          = (u64*)d_ws;
    unsigned* done_ctr = (unsigned*)(gseg + NSEG);

    // ws is re-poisoned by the harness every call: zero gseg + counter
    hipMemsetAsync(d_ws, 0, NSEG * sizeof(u64) + sizeof(u64), stream);

    const int nblocks = (n + EPB - 1) / EPB;
    seg_loss_kernel<<<nblocks, BLOCK, 0, stream>>>(
        reco, target, clabel, batch_index, gseg, done_ctr, (float*)d_out, n);
}

// Round 2
// 164.872 us; speedup vs baseline: 2.6319x; 2.6319x over previous
//
#include <hip/hip_runtime.h>

// AutoEncoderLoss: two-level segment-mean MSE over seg = b*128 + c.
// Strategy: per-half-wave-replicated LDS histogram of PACKED u64 accumulators
//   enc = (1 << 44) | round(d^2 * 2^20)   (count in high bits, fixed-point sum low)
// -> ONE native integer ds_add_u64 per element (no FP-atomic CAS loops).
// batch_index is sorted: per-block chunk is single-batch except ~31/1024
// boundary blocks -> fast path skips the per-element batch load entirely.
// Two-kernel pipeline (accum + tiny finalize). NO device fences / last-block
// pattern: round-1 measured __threadfence-per-block at ~10x regression
// (VALUBusy 0.7%, all waves parked on vmcnt(0) + L2 writeback).

#define BATCHES 32
#define CLUSTERS 128
#define NSEG (BATCHES * CLUSTERS)
#define BLOCK 256
#define EPB 8192                     // elements per block = 256 thr x 8 iter x 4
                                     // (halves flush-atomic count vs 4096)
#define REPL 8                       // 4 waves x 2 half-waves
#define RSTRIDE (2 * CLUSTERS + 4)   // 260 u64: +4 pad shifts replica bank phase
#define SHIFT 44
#define SCALE 1048576.0f             // 2^20
#define INV_SCALE (1.0f / 1048576.0f)
#define SUM_MASK ((1ULL << SHIFT) - 1)

typedef unsigned long long u64;

__device__ __forceinline__ u64 enc_elem(float d) {
    return (1ULL << SHIFT) + (u64)__float2uint_rn(d * d * SCALE);
}

__global__ __launch_bounds__(BLOCK) void seg_accum_kernel(
    const float* __restrict__ reco,
    const float* __restrict__ target,
    const int* __restrict__ clabel,
    const int* __restrict__ batch_index,
    u64* __restrict__ gseg,
    int n)
{
    // per-half-wave replica, 2 batches (b0, b0+1) x 128 clusters each
    __shared__ u64 hist[REPL * RSTRIDE];
    const int tid = threadIdx.x;

    for (int s = tid; s < REPL * RSTRIDE; s += BLOCK)
        hist[s] = 0ULL;
    __syncthreads();

    const long long base = (long long)blockIdx.x * EPB;
    if (base >= n) return;  // uniform per block, safe vs barriers
    const long long lim = (base + EPB <= (long long)n) ? base + EPB : (long long)n;

    const int b0 = batch_index[base];
    const int bL = batch_index[lim - 1];
    u64* h = &hist[(tid >> 5) * RSTRIDE];   // replica id = wave*2 + half-wave

    if (b0 == bL && base + EPB <= (long long)n) {
        // single-batch full chunk: no per-element batch load
        #pragma unroll
        for (int k = 0; k < EPB / (BLOCK * 4); ++k) {
            const long long idx = base + (long long)(k * BLOCK + tid) * 4;
            const float4 r = *(const float4*)(reco + idx);
            const float4 t = *(const float4*)(target + idx);
            const int4   c = *(const int4*)(clabel + idx);
            atomicAdd(&h[c.x], enc_elem(r.x - t.x));
            atomicAdd(&h[c.y], enc_elem(r.y - t.y));
            atomicAdd(&h[c.z], enc_elem(r.z - t.z));
            atomicAdd(&h[c.w], enc_elem(r.w - t.w));
        }
    } else {
        // boundary / tail path (rare): per-element batch
        for (long long idx = base + tid; idx < lim; idx += BLOCK) {
            const float d = reco[idx] - target[idx];
            const int b = batch_index[idx];
            const int c = clabel[idx];
            const u64 enc = enc_elem(d);
            const int rel = b - b0;
            if (rel < 2) atomicAdd(&h[rel * CLUSTERS + c], enc);
            else         atomicAdd(&gseg[(long long)b * CLUSTERS + c], enc);  // ~never
        }
    }
    __syncthreads();

    // combine replicas, sparse flush (zero entries skipped -> no OOB for the
    // unused upper half when b0 is the last batch)
    for (int s = tid; s < 2 * CLUSTERS; s += BLOCK) {
        u64 v = 0ULL;
        #pragma unroll
        for (int r = 0; r < REPL; ++r) v += hist[r * RSTRIDE + s];
        if (v) atomicAdd(&gseg[(long long)b0 * CLUSTERS + s], v);
    }
}

__global__ __launch_bounds__(256) void finalize_kernel(
    const u64* __restrict__ gseg,
    float* __restrict__ out)
{
    __shared__ float bl[BATCHES];
    __shared__ float bp[BATCHES];
    const int tid  = threadIdx.x;
    const int b    = tid >> 3;   // 32 batches x 8 threads
    const int part = tid & 7;

    float sm = 0.0f, np = 0.0f;
    #pragma unroll
    for (int j = 0; j < 16; ++j) {
        const u64 v = gseg[b * CLUSTERS + part * 16 + j];
        if (v) {  // nonzero iff count > 0
            const float cnt = (float)(unsigned)(v >> SHIFT);
            const float sum = (float)(v & SUM_MASK) * INV_SCALE;
            sm += sum / cnt;
            np += 1.0f;
        }
    }
    // reduce across the 8 threads per batch (contiguous lanes within a wave)
    #pragma unroll
    for (int off = 4; off; off >>= 1) {
        sm += __shfl_down(sm, off, 8);
        np += __shfl_down(np, off, 8);
    }
    if (part == 0) {
        bl[b] = (np > 0.0f) ? (sm / np) : 0.0f;
        bp[b] = (np > 0.0f) ? 1.0f : 0.0f;
    }
    __syncthreads();

    if (tid == 0) {
        float s = 0.0f, nb = 0.0f;
        #pragma unroll
        for (int i = 0; i < BATCHES; ++i) { s += bl[i]; nb += bp[i]; }
        out[0] = (nb > 0.0f) ? (s / nb) : 0.0f;
    }
}

extern "C" void kernel_launch(void* const* d_in, const int* in_sizes, int n_in,
                              void* d_out, int out_size, void* d_ws, size_t ws_size,
                              hipStream_t stream) {
    const float* reco        = (const float*)d_in[0];
    const float* target      = (const float*)d_in[1];
    const int*   clabel      = (const int*)d_in[2];
    const int*   batch_index = (const int*)d_in[3];
    const int n = in_sizes[0];

    u64* gseg = (u64*)d_ws;
    hipMemsetAsync(d_ws, 0, NSEG * sizeof(u64), stream);  // ws re-poisoned every call

    const int nblocks = (n + EPB - 1) / EPB;
    seg_accum_kernel<<<nblocks, BLOCK, 0, stream>>>(
        reco, target, clabel, batch_index, gseg, n);
    finalize_kernel<<<1, 256, 0, stream>>>(gseg, (float*)d_out);
}

// Round 3
// 158.372 us; speedup vs baseline: 2.7399x; 1.0410x over previous
//
#include <hip/hip_runtime.h>

// AutoEncoderLoss: two-level segment-mean MSE over seg = b*128 + c.
// Per-half-wave-replicated LDS histogram of PACKED u64 accumulators
//   enc = (1 << 44) | round(d^2 * 2^20)   (count high bits, fixed-point sum low)
// -> ONE native ds_add_u64 per element (fire-and-forget, no return use).
// batch_index sorted -> per-block chunk single-batch except ~31/2048 blocks.
//
// Round-2 lesson: compiler compiled the unrolled loop at VGPR_Count=16 = one
// load in flight (MLP=1), occupancy 24% -> 45 us latency-bound. Fix: EPB back
// to 4096 (8 blocks/CU = full TLP) + explicit 2-deep load pipeline with named
// register groups (MLP=2, ~48 VGPR, still 8 waves/SIMD).
// Round-1 lesson: NO per-block __threadfence / last-block finalize (10x).

#define BATCHES 32
#define CLUSTERS 128
#define NSEG (BATCHES * CLUSTERS)
#define BLOCK 256
#define EPB 4096                     // 256 thr x 4 groups x 4 elems
#define GROUPS (EPB / (BLOCK * 4))   // 4
#define REPL 8                       // 4 waves x 2 half-waves
#define RSTRIDE (2 * CLUSTERS + 4)   // 260 u64: +4 pad shifts replica bank phase
#define SHIFT 44
#define SCALE 1048576.0f             // 2^20
#define INV_SCALE (1.0f / 1048576.0f)
#define SUM_MASK ((1ULL << SHIFT) - 1)

typedef unsigned long long u64;

__device__ __forceinline__ u64 enc_elem(float d) {
    return (1ULL << SHIFT) + (u64)__float2uint_rn(d * d * SCALE);
}

__global__ __launch_bounds__(BLOCK) void seg_accum_kernel(
    const float* __restrict__ reco,
    const float* __restrict__ target,
    const int* __restrict__ clabel,
    const int* __restrict__ batch_index,
    u64* __restrict__ gseg,
    int n)
{
    __shared__ u64 hist[REPL * RSTRIDE];
    const int tid = threadIdx.x;

    for (int s = tid; s < REPL * RSTRIDE; s += BLOCK)
        hist[s] = 0ULL;
    __syncthreads();

    const long long base = (long long)blockIdx.x * EPB;
    if (base >= n) return;  // uniform per block, safe vs barriers
    const long long lim = (base + EPB <= (long long)n) ? base + EPB : (long long)n;

    const int b0 = batch_index[base];
    const int bL = batch_index[lim - 1];
    u64* h = &hist[(tid >> 5) * RSTRIDE];   // replica id = wave*2 + half-wave

    if (b0 == bL && base + EPB <= (long long)n) {
        // single-batch full chunk, 2-deep software-pipelined loads
        long long idx0 = base + (long long)tid * 4;
        float4 rA = *(const float4*)(reco + idx0);
        float4 tA = *(const float4*)(target + idx0);
        int4   cA = *(const int4*)(clabel + idx0);

        long long idx1 = idx0 + BLOCK * 4;
        float4 rB = *(const float4*)(reco + idx1);
        float4 tB = *(const float4*)(target + idx1);
        int4   cB = *(const int4*)(clabel + idx1);

        #pragma unroll
        for (int k = 0; k < GROUPS; ++k) {
            float4 rC, tC; int4 cC;
            if (k + 2 < GROUPS) {
                const long long idx = base + (long long)((k + 2) * BLOCK + tid) * 4;
                rC = *(const float4*)(reco + idx);
                tC = *(const float4*)(target + idx);
                cC = *(const int4*)(clabel + idx);
            }
            atomicAdd(&h[cA.x], enc_elem(rA.x - tA.x));
            atomicAdd(&h[cA.y], enc_elem(rA.y - tA.y));
            atomicAdd(&h[cA.z], enc_elem(rA.z - tA.z));
            atomicAdd(&h[cA.w], enc_elem(rA.w - tA.w));
            rA = rB; tA = tB; cA = cB;
            if (k + 2 < GROUPS) { rB = rC; tB = tC; cB = cC; }
        }
    } else {
        // boundary / tail path (rare): per-element batch
        for (long long idx = base + tid; idx < lim; idx += BLOCK) {
            const float d = reco[idx] - target[idx];
            const int b = batch_index[idx];
            const int c = clabel[idx];
            const u64 enc = enc_elem(d);
            const int rel = b - b0;
            if (rel < 2) atomicAdd(&h[rel * CLUSTERS + c], enc);
            else         atomicAdd(&gseg[(long long)b * CLUSTERS + c], enc);  // ~never
        }
    }
    __syncthreads();

    // combine replicas, sparse flush (zero entries skipped -> no OOB for the
    // unused upper half when b0 is the last batch)
    for (int s = tid; s < 2 * CLUSTERS; s += BLOCK) {
        u64 v = 0ULL;
        #pragma unroll
        for (int r = 0; r < REPL; ++r) v += hist[r * RSTRIDE + s];
        if (v) atomicAdd(&gseg[(long long)b0 * CLUSTERS + s], v);
    }
}

__global__ __launch_bounds__(256) void finalize_kernel(
    const u64* __restrict__ gseg,
    float* __restrict__ out)
{
    __shared__ float bl[BATCHES];
    __shared__ float bp[BATCHES];
    const int tid  = threadIdx.x;
    const int b    = tid >> 3;   // 32 batches x 8 threads
    const int part = tid & 7;

    float sm = 0.0f, np = 0.0f;
    #pragma unroll
    for (int j = 0; j < 16; ++j) {
        const u64 v = gseg[b * CLUSTERS + part * 16 + j];
        if (v) {  // nonzero iff count > 0
            const float cnt = (float)(unsigned)(v >> SHIFT);
            const float sum = (float)(v & SUM_MASK) * INV_SCALE;
            sm += sum / cnt;
            np += 1.0f;
        }
    }
    #pragma unroll
    for (int off = 4; off; off >>= 1) {
        sm += __shfl_down(sm, off, 8);
        np += __shfl_down(np, off, 8);
    }
    if (part == 0) {
        bl[b] = (np > 0.0f) ? (sm / np) : 0.0f;
        bp[b] = (np > 0.0f) ? 1.0f : 0.0f;
    }
    __syncthreads();

    if (tid == 0) {
        float s = 0.0f, nb = 0.0f;
        #pragma unroll
        for (int i = 0; i < BATCHES; ++i) { s += bl[i]; nb += bp[i]; }
        out[0] = (nb > 0.0f) ? (s / nb) : 0.0f;
    }
}

extern "C" void kernel_launch(void* const* d_in, const int* in_sizes, int n_in,
                              void* d_out, int out_size, void* d_ws, size_t ws_size,
                              hipStream_t stream) {
    const float* reco        = (const float*)d_in[0];
    const float* target      = (const float*)d_in[1];
    const int*   clabel      = (const int*)d_in[2];
    const int*   batch_index = (const int*)d_in[3];
    const int n = in_sizes[0];

    u64* gseg = (u64*)d_ws;
    hipMemsetAsync(d_ws, 0, NSEG * sizeof(u64), stream);  // ws re-poisoned every call

    const int nblocks = (n + EPB - 1) / EPB;
    seg_accum_kernel<<<nblocks, BLOCK, 0, stream>>>(
        reco, target, clabel, batch_index, gseg, n);
    finalize_kernel<<<1, 256, 0, stream>>>(gseg, (float*)d_out);
}

// Round 4
// 154.201 us; speedup vs baseline: 2.8140x; 1.0270x over previous
//
#include <hip/hip_runtime.h>

// AutoEncoderLoss: two-level segment-mean MSE over seg = b*128 + c.
// Per-half-wave-replicated LDS histogram of PACKED u64 accumulators
//   enc = (1 << 44) | round(d^2 * 2^20)   (count high bits, fixed-point sum low)
// -> ONE native ds_add_u64 per element (fire-and-forget, no return use).
// batch_index sorted -> per-block chunk single-batch except ~31/2048 blocks.
//
// Round-2 lesson: VGPR16/MLP1 + 4 blocks/CU = 45 us latency-bound.
// Round-3 lesson: 2-deep pipeline only recovered round-0 (~38 us, ~2.5 TB/s
//   effective). This round: ALL 12 16B loads issued up front (MLP=12/wave),
//   boundary path vectorized (no scalar straggler blocks).
// Round-1 lesson: NO per-block __threadfence / last-block finalize (10x).

#define BATCHES 32
#define CLUSTERS 128
#define NSEG (BATCHES * CLUSTERS)
#define BLOCK 256
#define EPB 4096                     // 256 thr x 4 groups x 4 elems
#define GROUPS (EPB / (BLOCK * 4))   // 4
#define REPL 8                       // 4 waves x 2 half-waves
#define RSTRIDE (2 * CLUSTERS + 4)   // 260 u64: +4 pad shifts replica bank phase
#define SHIFT 44
#define SCALE 1048576.0f             // 2^20
#define INV_SCALE (1.0f / 1048576.0f)
#define SUM_MASK ((1ULL << SHIFT) - 1)

typedef unsigned long long u64;

__device__ __forceinline__ u64 enc_elem(float d) {
    return (1ULL << SHIFT) + (u64)__float2uint_rn(d * d * SCALE);
}

__global__ __launch_bounds__(BLOCK) void seg_accum_kernel(
    const float* __restrict__ reco,
    const float* __restrict__ target,
    const int* __restrict__ clabel,
    const int* __restrict__ batch_index,
    u64* __restrict__ gseg,
    int n)
{
    __shared__ u64 hist[REPL * RSTRIDE];
    const int tid = threadIdx.x;

    for (int s = tid; s < REPL * RSTRIDE; s += BLOCK)
        hist[s] = 0ULL;
    __syncthreads();

    const long long base = (long long)blockIdx.x * EPB;
    if (base >= n) return;  // uniform per block, safe vs barriers
    const long long lim = (base + EPB <= (long long)n) ? base + EPB : (long long)n;

    const int b0 = batch_index[base];
    const int bL = batch_index[lim - 1];
    u64* h = &hist[(tid >> 5) * RSTRIDE];   // replica id = wave*2 + half-wave

    if (b0 == bL && base + EPB <= (long long)n) {
        // single-batch full chunk: issue ALL loads first (12 x 16B in flight
        // per wave), then consume. Static indices -> stays in registers.
        float4 r0, r1, r2, r3, t0, t1, t2, t3;
        int4   c0, c1, c2, c3;
        {
            const long long i0 = base + (long long)(0 * BLOCK + tid) * 4;
            const long long i1 = base + (long long)(1 * BLOCK + tid) * 4;
            const long long i2 = base + (long long)(2 * BLOCK + tid) * 4;
            const long long i3 = base + (long long)(3 * BLOCK + tid) * 4;
            r0 = *(const float4*)(reco + i0);
            r1 = *(const float4*)(reco + i1);
            r2 = *(const float4*)(reco + i2);
            r3 = *(const float4*)(reco + i3);
            t0 = *(const float4*)(target + i0);
            t1 = *(const float4*)(target + i1);
            t2 = *(const float4*)(target + i2);
            t3 = *(const float4*)(target + i3);
            c0 = *(const int4*)(clabel + i0);
            c1 = *(const int4*)(clabel + i1);
            c2 = *(const int4*)(clabel + i2);
            c3 = *(const int4*)(clabel + i3);
        }
        atomicAdd(&h[c0.x], enc_elem(r0.x - t0.x));
        atomicAdd(&h[c0.y], enc_elem(r0.y - t0.y));
        atomicAdd(&h[c0.z], enc_elem(r0.z - t0.z));
        atomicAdd(&h[c0.w], enc_elem(r0.w - t0.w));
        atomicAdd(&h[c1.x], enc_elem(r1.x - t1.x));
        atomicAdd(&h[c1.y], enc_elem(r1.y - t1.y));
        atomicAdd(&h[c1.z], enc_elem(r1.z - t1.z));
        atomicAdd(&h[c1.w], enc_elem(r1.w - t1.w));
        atomicAdd(&h[c2.x], enc_elem(r2.x - t2.x));
        atomicAdd(&h[c2.y], enc_elem(r2.y - t2.y));
        atomicAdd(&h[c2.z], enc_elem(r2.z - t2.z));
        atomicAdd(&h[c2.w], enc_elem(r2.w - t2.w));
        atomicAdd(&h[c3.x], enc_elem(r3.x - t3.x));
        atomicAdd(&h[c3.y], enc_elem(r3.y - t3.y));
        atomicAdd(&h[c3.z], enc_elem(r3.z - t3.z));
        atomicAdd(&h[c3.w], enc_elem(r3.w - t3.w));
    } else if (base + EPB <= (long long)n) {
        // boundary block (spans 2 batches, ~31/2048): vectorized, per-element
        // batch via int4 load of batch_index.
        #pragma unroll
        for (int k = 0; k < GROUPS; ++k) {
            const long long idx = base + (long long)(k * BLOCK + tid) * 4;
            const float4 r = *(const float4*)(reco + idx);
            const float4 t = *(const float4*)(target + idx);
            const int4   c = *(const int4*)(clabel + idx);
            const int4   b = *(const int4*)(batch_index + idx);
            const int rx = b.x - b0, ry = b.y - b0, rz = b.z - b0, rw = b.w - b0;
            const u64 ex = enc_elem(r.x - t.x), ey = enc_elem(r.y - t.y);
            const u64 ez = enc_elem(r.z - t.z), ew = enc_elem(r.w - t.w);
            if (rx < 2) atomicAdd(&h[rx * CLUSTERS + c.x], ex);
            else        atomicAdd(&gseg[(long long)b.x * CLUSTERS + c.x], ex);
            if (ry < 2) atomicAdd(&h[ry * CLUSTERS + c.y], ey);
            else        atomicAdd(&gseg[(long long)b.y * CLUSTERS + c.y], ey);
            if (rz < 2) atomicAdd(&h[rz * CLUSTERS + c.z], ez);
            else        atomicAdd(&gseg[(long long)b.z * CLUSTERS + c.z], ez);
            if (rw < 2) atomicAdd(&h[rw * CLUSTERS + c.w], ew);
            else        atomicAdd(&gseg[(long long)b.w * CLUSTERS + c.w], ew);
        }
    } else {
        // ragged tail (n not multiple of EPB; never hit for N=2^23): scalar
        for (long long idx = base + tid; idx < lim; idx += BLOCK) {
            const float d = reco[idx] - target[idx];
            const int b = batch_index[idx];
            const int c = clabel[idx];
            const u64 enc = enc_elem(d);
            const int rel = b - b0;
            if (rel < 2) atomicAdd(&h[rel * CLUSTERS + c], enc);
            else         atomicAdd(&gseg[(long long)b * CLUSTERS + c], enc);
        }
    }
    __syncthreads();

    // combine replicas, sparse flush (zero entries skipped -> no OOB for the
    // unused upper half when b0 is the last batch)
    for (int s = tid; s < 2 * CLUSTERS; s += BLOCK) {
        u64 v = 0ULL;
        #pragma unroll
        for (int r = 0; r < REPL; ++r) v += hist[r * RSTRIDE + s];
        if (v) atomicAdd(&gseg[(long long)b0 * CLUSTERS + s], v);
    }
}

__global__ __launch_bounds__(256) void finalize_kernel(
    const u64* __restrict__ gseg,
    float* __restrict__ out)
{
    __shared__ float bl[BATCHES];
    __shared__ float bp[BATCHES];
    const int tid  = threadIdx.x;
    const int b    = tid >> 3;   // 32 batches x 8 threads
    const int part = tid & 7;

    float sm = 0.0f, np = 0.0f;
    #pragma unroll
    for (int j = 0; j < 16; ++j) {
        const u64 v = gseg[b * CLUSTERS + part * 16 + j];
        if (v) {  // nonzero iff count > 0
            const float cnt = (float)(unsigned)(v >> SHIFT);
            const float sum = (float)(v & SUM_MASK) * INV_SCALE;
            sm += sum / cnt;
            np += 1.0f;
        }
    }
    #pragma unroll
    for (int off = 4; off; off >>= 1) {
        sm += __shfl_down(sm, off, 8);
        np += __shfl_down(np, off, 8);
    }
    if (part == 0) {
        bl[b] = (np > 0.0f) ? (sm / np) : 0.0f;
        bp[b] = (np > 0.0f) ? 1.0f : 0.0f;
    }
    __syncthreads();

    if (tid == 0) {
        float s = 0.0f, nb = 0.0f;
        #pragma unroll
        for (int i = 0; i < BATCHES; ++i) { s += bl[i]; nb += bp[i]; }
        out[0] = (nb > 0.0f) ? (s / nb) : 0.0f;
    }
}

extern "C" void kernel_launch(void* const* d_in, const int* in_sizes, int n_in,
                              void* d_out, int out_size, void* d_ws, size_t ws_size,
                              hipStream_t stream) {
    const float* reco        = (const float*)d_in[0];
    const float* target      = (const float*)d_in[1];
    const int*   clabel      = (const int*)d_in[2];
    const int*   batch_index = (const int*)d_in[3];
    const int n = in_sizes[0];

    u64* gseg = (u64*)d_ws;
    hipMemsetAsync(d_ws, 0, NSEG * sizeof(u64), stream);  // ws re-poisoned every call

    const int nblocks = (n + EPB - 1) / EPB;
    seg_accum_kernel<<<nblocks, BLOCK, 0, stream>>>(
        reco, target, clabel, batch_index, gseg, n);
    finalize_kernel<<<1, 256, 0, stream>>>(gseg, (float*)d_out);
}